// Round 11
// baseline (312.169 us; speedup 1.0000x reference)
//
#include <hip/hip_runtime.h>
#include <math.h>

typedef unsigned short u16;
typedef unsigned int   u32;

using f32x4  = __attribute__((ext_vector_type(4))) float;
using s16x8  = __attribute__((ext_vector_type(8))) short;
using u16x8  = __attribute__((ext_vector_type(8))) unsigned short;

// ---------- helpers ----------
__device__ __forceinline__ u16 f2b(float f) {           // fp32 -> bf16 RNE
    u32 u = __float_as_uint(f);
    u += 0x7FFFu + ((u >> 16) & 1u);
    return (u16)(u >> 16);
}
__device__ __forceinline__ float b2f(u16 u) { return __uint_as_float(((u32)u) << 16); }

// window-order row R -> natural token row (b*256 + i*16 + j)
__device__ __forceinline__ int natrow(int R) {
    int b = R >> 8, r8 = R & 255, w = r8 >> 2, t = r8 & 3;
    return (b << 8) + ((((w >> 3) << 1) + (t >> 1)) << 4) + ((w & 7) << 1) + (t & 1);
}

__device__ __forceinline__ void gll16(const void* g, void* l) {
    __builtin_amdgcn_global_load_lds(
        (const __attribute__((address_space(1))) void*)g,
        (__attribute__((address_space(3))) void*)l, 16, 0, 0);
}

// ---------- weight repack: [R][C] f32 -> [C][R] bf16 ----------
__device__ __forceinline__ void transpose_body(
    const float* __restrict__ in, u16* __restrict__ out, int R, int C)
{
    __shared__ float tile[32][33];
    const int tx = threadIdx.x, ty = threadIdx.y;
    const int c  = blockIdx.x * 32 + tx;
    const int r0 = blockIdx.y * 32;
#pragma unroll
    for (int i = 0; i < 32; i += 8) tile[ty + i][tx] = in[(size_t)(r0 + ty + i) * C + c];
    __syncthreads();
    const int orow0 = blockIdx.x * 32;
    const int ocol  = r0 + tx;
#pragma unroll
    for (int i = 0; i < 32; i += 8)
        out[(size_t)(orow0 + ty + i) * R + ocol] = f2b(tile[tx][ty + i]);
}

// z in [0,48): Wq heads 0-15, Wk 16-31, Wv 32-47; each head [1024][64] -> [64][1024]
__global__ __launch_bounds__(256) void transpose_qkv(
    const float* __restrict__ Wq, const float* __restrict__ Wk,
    const float* __restrict__ Wv, u16* __restrict__ out)
{
    const int z = blockIdx.z;
    const float* in = (z < 16 ? Wq : z < 32 ? Wk : Wv) + (size_t)(z & 15) * 65536;
    transpose_body(in, out + (size_t)z * 65536, 1024, 64);
}

// z in [0,3): Wp, W1, W2; [1024][1024] -> transposed, outputs contiguous
__global__ __launch_bounds__(256) void transpose_pw(
    const float* __restrict__ Wp, const float* __restrict__ W1,
    const float* __restrict__ W2, u16* __restrict__ out)
{
    const int z = blockIdx.z;
    const float* in = z == 0 ? Wp : z == 1 ? W1 : W2;
    transpose_body(in, out + (size_t)z * 1048576, 1024, 1024);
}

// ---------- LayerNorm; MAP = window-gather rows, BIN = bf16 input ----------
template<int MAP, int BIN>
__global__ __launch_bounds__(256) void ln_kernel(
    const void* __restrict__ X, const float* __restrict__ g, const float* __restrict__ bta,
    u16* __restrict__ outB)
{
    const int R   = blockIdx.x;
    const int src = MAP ? natrow(R) : R;
    float x0, x1, x2, x3;
    if (BIN) {
        const ushort4 r = ((const ushort4*)((const u16*)X + (size_t)src * 1024))[threadIdx.x];
        x0 = b2f(r.x); x1 = b2f(r.y); x2 = b2f(r.z); x3 = b2f(r.w);
    } else {
        const float4 r = ((const float4*)((const float*)X + (size_t)src * 1024))[threadIdx.x];
        x0 = r.x; x1 = r.y; x2 = r.z; x3 = r.w;
    }
    float s  = x0 + x1 + x2 + x3;
    float s2 = x0 * x0 + x1 * x1 + x2 * x2 + x3 * x3;
#pragma unroll
    for (int o = 32; o; o >>= 1) { s += __shfl_xor(s, o); s2 += __shfl_xor(s2, o); }
    __shared__ float red[8];
    const int w = threadIdx.x >> 6, l = threadIdx.x & 63;
    if (l == 0) { red[w] = s; red[w + 4] = s2; }
    __syncthreads();
    s  = red[0] + red[1] + red[2] + red[3];
    s2 = red[4] + red[5] + red[6] + red[7];
    const float mean = s * (1.f / 1024.f);
    const float var  = s2 * (1.f / 1024.f) - mean * mean;
    const float rinv = rsqrtf(var + 1e-5f);
    const float4 gv = ((const float4*)g)[threadIdx.x];
    const float4 bv = ((const float4*)bta)[threadIdx.x];
    ((ushort4*)(outB + (size_t)R * 1024))[threadIdx.x] = make_ushort4(
        f2b((x0 - mean) * rinv * gv.x + bv.x), f2b((x1 - mean) * rinv * gv.y + bv.y),
        f2b((x2 - mean) * rinv * gv.z + bv.z), f2b((x3 - mean) * rinv * gv.w + bv.w));
}

// ---------- 256x256 8-wave GEMM, BK=64, in-tile read/MFMA software pipeline ----------
// C[M][N] = A[M][K](bf16, row stride LDA) @ Bt[N][K](bf16)^T
// MODE 0: bf16            MODE 2: gelu(+bias) -> bf16
// MODE 3: +bias + bf16 resid -> f32 at natrow     MODE 5: +bias + bf16 resid -> bf16
//
// Block order: XCD stripe + 4x4 (mb,nb) sub-chunks (4MB L2 working set) [r9].
// LDS (128KB): A [d][half][128 rows][128B] at d*32K+half*16K; B at +64KB.
// Swizzle (3-bit): phys_byte = lin_byte ^ ((row&7)<<4); gll sources pre-permuted
// by same involution in 16B chunks: q = p ^ ((p>>3)&7).  (conflict-free, r3 PMC)
//
// r11 pipeline (lgkmcnt is 4-bit, waits <= 6 here): ONE barrier + ONE vmcnt(0)
// per tile at entry (awaited stages issued ~one tile earlier -> no stall).
// Interleaved issue/wait schedule, per-wave in-order DS retire accounting:
//   issue 12 (a0,b0 both kk) | stages | WL6  -> M8 q00 kk0
//   issue 4 (a1 kk0)         |        | WL4  -> M8 q00 kk1
//   issue 4 (a1 kk1)         |        | WL4  -> M8 q10 kk0
//   issue 2 (b1 kk0)         |        | WL2  -> M8 q10 kk1
//   issue 2 (b1 kk1)         |        | WL2  -> M8 q11 kk0
//                                       WL0  -> M8 q11 kk1, q01 kk0, q01 kk1
// Later reads drain UNDER earlier MFMAs -> LDS pipe (~2300cyc/tile) overlaps
// MFMA pipe (~2480cyc/tile) instead of serializing. Max outstanding 12.
// WAR safety: WL0 precedes the next tile-entry barrier; stages target the
// other buffer and issue only after that barrier.
template<int MODE>
__global__ __launch_bounds__(512, 2) void gemm256(
    const u16* __restrict__ A, const u16* __restrict__ Bt,
    const float* __restrict__ bias, const void* __restrict__ resid,
    void* __restrict__ Out, int M, int N, int K, int LDA, int NB)
{
    extern __shared__ char lds[];
    const int NT = K >> 6;
    const int nblk = gridDim.x;
    // --- 2D sub-chunked XCD ordering ---
    const int x = blockIdx.x & 7, i = blockIdx.x >> 3;
    const int R = (nblk >> 3) / NB;               // mb-rows per XCD stripe
    const int ncs = NB >> 2;                      // sub-chunk columns
    const int sc = i >> 4, u = i & 15;
    const int scr = sc / ncs, scc = sc - scr * ncs;
    const int mb = x * R + scr * 4 + (u >> 2);
    const int nb = scc * 4 + (u & 3);
    const int row0 = mb * 256, col0 = nb * 256;
    const int tid = threadIdx.x;
    const int w = tid >> 6, l = tid & 63;
    const int wr = w >> 2, wc = w & 3;
    const int lr = l & 15, kg = l >> 4;
    const int xs = (lr & 7) << 4;
    const int koff[2] = { (kg * 16) ^ xs, (64 + kg * 16) ^ xs };
    const int abase_l = wr * 8192 + lr * 128;
    const int bbase_l = wc * 4096 + lr * 128;

    f32x4 acc[2][2][4][2] = {};                   // [qm][qn][i][n]
    s16x8 a0[4][2], a1[4][2], b0[2][2], b1[2][2];

    auto stage = [&](int ts, int item) {          // item: 0=A0 1=B0 2=A1 3=B1
        if (ts >= NT) return;
        const int d = ts & 1;
        const int isB = item & 1, h = item >> 1;
        char* lbase = lds + (isB ? 65536 : 0) + d * 32768 + h * 16384;
        const u16* gptr = isB ? Bt : A;
        const int ld = isB ? K : LDA;
        const int blk0 = (isB ? col0 : row0) + h * 128;
#pragma unroll
        for (int j = 0; j < 2; ++j) {
            const int p = j * 512 + tid;
            const int q = p ^ ((p >> 3) & 7);     // involution, row-preserving
            const int grow = blk0 + (q >> 3);
            const int gcol = ts * 64 + (q & 7) * 8;
            gll16(gptr + (size_t)grow * ld + gcol, lbase + (j * 8 + w) * 1024);
        }
    };

#define SB __builtin_amdgcn_sched_barrier(0)
#define RDA(dst, qm, kk) do { \
    _Pragma("unroll") for (int i2 = 0; i2 < 4; ++i2) \
        dst[i2][kk] = *(const s16x8*)(Ab + (qm) * 16384 + abase_l + i2 * 2048 + koff[kk]); \
} while (0)
#define RDB(dst, qn, kk) do { \
    _Pragma("unroll") for (int n = 0; n < 2; ++n) \
        dst[n][kk] = *(const s16x8*)(Bb + (qn) * 16384 + bbase_l + n * 2048 + koff[kk]); \
} while (0)
#define WL(NS) do { \
    asm volatile("s_waitcnt lgkmcnt(" NS ")" ::: "memory"); SB; \
} while (0)
#define M8(qm, qn, aa, bb, kk) do { \
    _Pragma("unroll") for (int i2 = 0; i2 < 4; ++i2) \
    _Pragma("unroll") for (int n = 0; n < 2; ++n) \
        acc[qm][qn][i2][n] = __builtin_amdgcn_mfma_f32_16x16x32_bf16( \
            aa[i2][kk], bb[n][kk], acc[qm][qn][i2][n], 0, 0, 0); \
    SB; \
} while (0)

    // prologue: stage tile 0's four half-tiles
    stage(0, 0); stage(0, 1); stage(0, 2); stage(0, 3);

    for (int t = 0; t < NT; ++t) {
        const char* Ab = lds + (t & 1) * 32768;
        const char* Bb = lds + 65536 + (t & 1) * 32768;
        // tile-entry gate: own stages (issued ~1 tile ago) + barrier
        asm volatile("s_waitcnt vmcnt(0)" ::: "memory");
        __builtin_amdgcn_s_barrier(); SB;
        // G1+G2: a0,b0 both kk (12 reads)
        RDA(a0, 0, 0); RDB(b0, 0, 0); SB;
        RDA(a0, 0, 1); RDB(b0, 0, 1); SB;
        // next-tile stages (vmcnt domain; age ~= one tile at next gate)
        stage(t + 1, 0); stage(t + 1, 1); stage(t + 1, 2); stage(t + 1, 3);
        SB;
        __builtin_amdgcn_s_setprio(1);
        WL("6");  M8(0, 0, a0, b0, 0);            // 6 done (a0,b0 kk0)
        RDA(a1, 1, 0); SB;                        // +4 (outstanding <=10)
        WL("4");  M8(0, 0, a0, b0, 1);            // 12 done (a0,b0 kk1)
        RDA(a1, 1, 1); SB;                        // +4 (<=8)
        WL("4");  M8(1, 0, a1, b0, 0);            // 16 done (a1 kk0)
        RDB(b1, 1, 0); SB;                        // +2 (<=6)
        WL("2");  M8(1, 0, a1, b0, 1);            // 20 done (a1 kk1)
        RDB(b1, 1, 1); SB;                        // +2 (<=4)
        WL("2");  M8(1, 1, a1, b1, 0);            // 22 done (b1 kk0)
        WL("0");  M8(1, 1, a1, b1, 1);            // all 24 done
                  M8(0, 1, a0, b1, 0);
                  M8(0, 1, a0, b1, 1);
        __builtin_amdgcn_s_setprio(0); SB;
    }
#undef SB
#undef RDA
#undef RDB
#undef WL
#undef M8

    // epilogue
#pragma unroll
    for (int qm = 0; qm < 2; ++qm)
#pragma unroll
    for (int i2 = 0; i2 < 4; ++i2) {
        const int grb = row0 + qm * 128 + wr * 64 + i2 * 16 + kg * 4;
#pragma unroll
        for (int qn = 0; qn < 2; ++qn)
#pragma unroll
        for (int n = 0; n < 2; ++n) {
            const int gc = col0 + qn * 128 + wc * 32 + n * 16 + lr;
#pragma unroll
            for (int j = 0; j < 4; ++j) {
                const int gr = grb + j;
                const float v = acc[qm][qn][i2][n][j];
                if (MODE == 0) {
                    ((u16*)Out)[(size_t)gr * N + gc] = f2b(v);
                } else if (MODE == 2) {
                    const float tt = v + bias[gc];
                    ((u16*)Out)[(size_t)gr * N + gc] = f2b(0.5f * tt * (1.f + erff(tt * 0.70710678118f)));
                } else if (MODE == 3) {
                    ((float*)Out)[(size_t)natrow(gr) * N + gc] =
                        v + bias[gc] + b2f(((const u16*)resid)[(size_t)gr * N + gc]);
                } else {
                    ((u16*)Out)[(size_t)gr * N + gc] =
                        f2b(v + bias[gc] + b2f(((const u16*)resid)[(size_t)gr * N + gc]));
                }
            }
        }
    }
}

// ---------- tiny windowed attention, vectorized short8, in-place into q cols ----------
// one wave per window; lane l, chunk c covers cols c*512 + l*8 (head = c*8 + (l>>3))
__global__ __launch_bounds__(256) void attn_kernel(u16* __restrict__ QKV)
{
    const int w = threadIdx.x >> 6, l = threadIdx.x & 63;
    const int n = blockIdx.x * 4 + w;             // 4096 windows
    u16* base = QKV + (size_t)n * 4 * 3072;
    const float scale = 0.03125f;                 // C^-0.5 = 1/32 (d_model!)
#pragma unroll
    for (int c = 0; c < 2; ++c) {
        const int col = c * 512 + l * 8;
        u16x8 qr[4], kr[4], vr[4];
#pragma unroll
        for (int t = 0; t < 4; ++t) {
            qr[t] = *(const u16x8*)(base + t * 3072 + col);
            kr[t] = *(const u16x8*)(base + t * 3072 + 1024 + col);
            vr[t] = *(const u16x8*)(base + t * 3072 + 2048 + col);
        }
        float qf[4][8], kf[4][8];
#pragma unroll
        for (int t = 0; t < 4; ++t)
#pragma unroll
            for (int j = 0; j < 8; ++j) { qf[t][j] = b2f(qr[t][j]); kf[t][j] = b2f(kr[t][j]); }
        float s[4][4];
#pragma unroll
        for (int t = 0; t < 4; ++t)
#pragma unroll
            for (int u = 0; u < 4; ++u) {
                float p = qf[t][0] * kf[u][0];
#pragma unroll
                for (int j = 1; j < 8; ++j) p += qf[t][j] * kf[u][j];
                p += __shfl_xor(p, 1); p += __shfl_xor(p, 2); p += __shfl_xor(p, 4);
                s[t][u] = p * scale;              // per-head dot (8-lane group)
            }
#pragma unroll
        for (int t = 0; t < 4; ++t) {
            const float m = fmaxf(fmaxf(s[t][0], s[t][1]), fmaxf(s[t][2], s[t][3]));
            const float e0 = expf(s[t][0] - m), e1 = expf(s[t][1] - m);
            const float e2 = expf(s[t][2] - m), e3 = expf(s[t][3] - m);
            const float inv = 1.f / (e0 + e1 + e2 + e3);
            u16x8 o;
#pragma unroll
            for (int j = 0; j < 8; ++j)
                o[j] = f2b((e0 * b2f(vr[0][j]) + e1 * b2f(vr[1][j]) +
                            e2 * b2f(vr[2][j]) + e3 * b2f(vr[3][j])) * inv);
            *(u16x8*)(base + t * 3072 + col) = o; // overwrite own q slot (wave-private)
        }
    }
}

// ---------- launch ----------
extern "C" void kernel_launch(void* const* d_in, const int* in_sizes, int n_in,
                              void* d_out, int out_size, void* d_ws, size_t ws_size,
                              hipStream_t stream)
{
    const float* x    = (const float*)d_in[0];
    const float* ln1g = (const float*)d_in[1];
    const float* ln1b = (const float*)d_in[2];
    const float* Wq   = (const float*)d_in[3];
    const float* Wk   = (const float*)d_in[4];
    const float* Wv   = (const float*)d_in[5];
    const float* Wp   = (const float*)d_in[6];
    const float* bp   = (const float*)d_in[7];
    const float* ln2g = (const float*)d_in[8];
    const float* ln2b = (const float*)d_in[9];
    const float* W1   = (const float*)d_in[10];
    const float* b1   = (const float*)d_in[11];
    const float* W2   = (const float*)d_in[12];
    const float* b2   = (const float*)d_in[13];
    float* out = (float*)d_out;

    char* ws = (char*)d_ws;
    const size_t MB = 1024 * 1024;
    u16* xr_b  = (u16*)ws;                        // 32MB: xr bf16 (residual spine)
    u16* xw_b  = (u16*)(ws + 32 * MB);            // 32MB: ln1(x) windowed bf16
    u16* qkv   = (u16*)(ws + 64 * MB);            // 96MB: q|k|v; attn in-place; dead after proj
    u16* h1b   = (u16*)(ws + 64 * MB);            // 32MB: reuse of qkv region after proj
    u16* ln2bf = (u16*)(ws + 160 * MB);           // 32MB
    u16* WqkvT = (u16*)(ws + 192 * MB);           // 6MB [3072][1024]
    u16* WpT   = (u16*)(ws + 198 * MB);           // 3 x 2MB contiguous
    u16* W1T   = WpT + (1u << 20);
    u16* W2T   = W1T + (1u << 20);

    (void)hipFuncSetAttribute((const void*)gemm256<0>, hipFuncAttributeMaxDynamicSharedMemorySize, 131072);
    (void)hipFuncSetAttribute((const void*)gemm256<2>, hipFuncAttributeMaxDynamicSharedMemorySize, 131072);
    (void)hipFuncSetAttribute((const void*)gemm256<3>, hipFuncAttributeMaxDynamicSharedMemorySize, 131072);
    (void)hipFuncSetAttribute((const void*)gemm256<5>, hipFuncAttributeMaxDynamicSharedMemorySize, 131072);

    const int M = 16384, K = 1024;
    dim3 tpb(32, 8);
    transpose_qkv<<<dim3(2, 32, 48), tpb, 0, stream>>>(Wq, Wk, Wv, WqkvT);
    transpose_pw <<<dim3(32, 32, 3), tpb, 0, stream>>>(Wp, W1, W2, WpT);

    ln_kernel<1, 0><<<16384, 256, 0, stream>>>(x, ln1g, ln1b, xw_b);

    // qkv = xw @ [Wq|Wk|Wv]   (N=3072)
    gemm256<0><<<768, 512, 131072, stream>>>(xw_b, WqkvT, nullptr, nullptr, qkv, M, 3072, K, K, 12);

    attn_kernel<<<1024, 256, 0, stream>>>(qkv);    // att overwrites q columns

    // xr = att @ Wp + bp + xw  -> bf16 spine
    gemm256<5><<<256, 512, 131072, stream>>>(qkv, WpT, bp, xw_b, xr_b, M, 1024, K, 3072, 4);

    ln_kernel<0, 1><<<16384, 256, 0, stream>>>(xr_b, ln2g, ln2b, ln2bf);

    // h1 = gelu(ln2 @ W1 + b1)
    gemm256<2><<<256, 512, 131072, stream>>>(ln2bf, W1T, b1, nullptr, h1b, M, 1024, K, K, 4);

    // out[natrow] = h1 @ W2 + b2 + xr
    gemm256<3><<<256, 512, 131072, stream>>>(h1b, W2T, b2, xr_b, out, M, 1024, K, K, 4);
}

// Round 12
// 289.709 us; speedup vs baseline: 1.0775x; 1.0775x over previous
//
#include <hip/hip_runtime.h>
#include <math.h>

typedef unsigned short u16;
typedef unsigned int   u32;

using f32x4  = __attribute__((ext_vector_type(4))) float;
using s16x8  = __attribute__((ext_vector_type(8))) short;
using u16x8  = __attribute__((ext_vector_type(8))) unsigned short;

// ---------- helpers ----------
__device__ __forceinline__ u16 f2b(float f) {           // fp32 -> bf16 RNE
    u32 u = __float_as_uint(f);
    u += 0x7FFFu + ((u >> 16) & 1u);
    return (u16)(u >> 16);
}
__device__ __forceinline__ float b2f(u16 u) { return __uint_as_float(((u32)u) << 16); }

// window-order row R -> natural token row (b*256 + i*16 + j)
__device__ __forceinline__ int natrow(int R) {
    int b = R >> 8, r8 = R & 255, w = r8 >> 2, t = r8 & 3;
    return (b << 8) + ((((w >> 3) << 1) + (t >> 1)) << 4) + ((w & 7) << 1) + (t & 1);
}

__device__ __forceinline__ void gll16(const void* g, void* l) {
    __builtin_amdgcn_global_load_lds(
        (const __attribute__((address_space(1))) void*)g,
        (__attribute__((address_space(3))) void*)l, 16, 0, 0);
}

// ---------- weight repack: [R][C] f32 -> [C][R] bf16 ----------
__device__ __forceinline__ void transpose_body(
    const float* __restrict__ in, u16* __restrict__ out, int R, int C)
{
    __shared__ float tile[32][33];
    const int tx = threadIdx.x, ty = threadIdx.y;
    const int c  = blockIdx.x * 32 + tx;
    const int r0 = blockIdx.y * 32;
#pragma unroll
    for (int i = 0; i < 32; i += 8) tile[ty + i][tx] = in[(size_t)(r0 + ty + i) * C + c];
    __syncthreads();
    const int orow0 = blockIdx.x * 32;
    const int ocol  = r0 + tx;
#pragma unroll
    for (int i = 0; i < 32; i += 8)
        out[(size_t)(orow0 + ty + i) * R + ocol] = f2b(tile[tx][ty + i]);
}

// z in [0,48): head-INTERLEAVED layout: head h occupies rows h*192..h*192+191 of
// the [3072][1024] Bt: q at +0, k at +64, v at +128.
__global__ __launch_bounds__(256) void transpose_qkv(
    const float* __restrict__ Wq, const float* __restrict__ Wk,
    const float* __restrict__ Wv, u16* __restrict__ out)
{
    const int z = blockIdx.z;
    const float* in = (z < 16 ? Wq : z < 32 ? Wk : Wv) + (size_t)(z & 15) * 65536;
    const int h = z & 15, sec = z < 16 ? 0 : (z < 32 ? 1 : 2);
    transpose_body(in, out + ((size_t)h * 192 + sec * 64) * 1024, 1024, 64);
}

// z in [0,3): Wp, W1, W2; [1024][1024] -> transposed, outputs contiguous
__global__ __launch_bounds__(256) void transpose_pw(
    const float* __restrict__ Wp, const float* __restrict__ W1,
    const float* __restrict__ W2, u16* __restrict__ out)
{
    const int z = blockIdx.z;
    const float* in = z == 0 ? Wp : z == 1 ? W1 : W2;
    transpose_body(in, out + (size_t)z * 1048576, 1024, 1024);
}

// ---------- LayerNorm; MAP = window-gather rows, BIN = bf16 input ----------
template<int MAP, int BIN>
__global__ __launch_bounds__(256) void ln_kernel(
    const void* __restrict__ X, const float* __restrict__ g, const float* __restrict__ bta,
    u16* __restrict__ outB)
{
    const int R   = blockIdx.x;
    const int src = MAP ? natrow(R) : R;
    float x0, x1, x2, x3;
    if (BIN) {
        const ushort4 r = ((const ushort4*)((const u16*)X + (size_t)src * 1024))[threadIdx.x];
        x0 = b2f(r.x); x1 = b2f(r.y); x2 = b2f(r.z); x3 = b2f(r.w);
    } else {
        const float4 r = ((const float4*)((const float*)X + (size_t)src * 1024))[threadIdx.x];
        x0 = r.x; x1 = r.y; x2 = r.z; x3 = r.w;
    }
    float s  = x0 + x1 + x2 + x3;
    float s2 = x0 * x0 + x1 * x1 + x2 * x2 + x3 * x3;
#pragma unroll
    for (int o = 32; o; o >>= 1) { s += __shfl_xor(s, o); s2 += __shfl_xor(s2, o); }
    __shared__ float red[8];
    const int w = threadIdx.x >> 6, l = threadIdx.x & 63;
    if (l == 0) { red[w] = s; red[w + 4] = s2; }
    __syncthreads();
    s  = red[0] + red[1] + red[2] + red[3];
    s2 = red[4] + red[5] + red[6] + red[7];
    const float mean = s * (1.f / 1024.f);
    const float var  = s2 * (1.f / 1024.f) - mean * mean;
    const float rinv = rsqrtf(var + 1e-5f);
    const float4 gv = ((const float4*)g)[threadIdx.x];
    const float4 bv = ((const float4*)bta)[threadIdx.x];
    ((ushort4*)(outB + (size_t)R * 1024))[threadIdx.x] = make_ushort4(
        f2b((x0 - mean) * rinv * gv.x + bv.x), f2b((x1 - mean) * rinv * gv.y + bv.y),
        f2b((x2 - mean) * rinv * gv.z + bv.z), f2b((x3 - mean) * rinv * gv.w + bv.w));
}

// ---------- FUSED QKV GEMM + windowed attention ----------
// A [16384][1024] bf16 (ln1 windowed), Bt [3072][1024] head-interleaved.
// Tile 256x192 (BN=192 = one head's q|k|v), BK=64, 8 waves as 4x2.
// Per block: compute q,k,v for 64 windows x 1 head entirely in acc, then
// attention in the epilogue (LDS bounce, 8 threads/window), write ONLY att.
// LDS: A [d][256 rows][128B] at d*32768 (64KB); B [d][192 rows][128B] at
// 65536 + d*24576 (48KB). Swizzle phys_byte = lin ^ ((row&7)<<4), gll sources
// pre-permuted by the same involution (conflict-free, r3 PMC).
// Attn staging reuses lds as [256][200] u16 (100KB) after the K-loop.
__global__ __launch_bounds__(512, 2) void gemm_qkv_attn(
    const u16* __restrict__ A, const u16* __restrict__ Bt,
    u16* __restrict__ Att, int M, int K)
{
    extern __shared__ char lds[];
    const int NT = K >> 6;                        // 16
    // 2D sub-chunked XCD ordering: nblk=1024, NB=16
    const int x = blockIdx.x & 7, i = blockIdx.x >> 3;
    const int sc = i >> 4, u = i & 15;
    const int scr = sc >> 2, scc = sc & 3;
    const int mb = x * 8 + scr * 4 + (u >> 2);
    const int nb = scc * 4 + (u & 3);             // head index 0..15
    const int row0 = mb * 256, col0 = nb * 192;
    const int tid = threadIdx.x;
    const int w = tid >> 6, l = tid & 63;
    const int wr = w & 3, wcg = w >> 2;           // 4 row-groups x 2 col-groups
    const int lr = l & 15, kg = l >> 4;
    const int xs = (lr & 7) << 4;
    const int koff[2] = { (kg * 16) ^ xs, (64 + kg * 16) ^ xs };
    const int abase_l = wr * 8192 + lr * 128;     // rows wr*64.. (x128B)
    const int bbase_l = wcg * 12288 + lr * 128;   // rows wcg*96.. (x128B)

    f32x4 acc[4][6] = {};
    s16x8 a[4][2], b[6][2];

    auto stageQ = [&](int ts) {
        if (ts >= NT) return;
        const int d = ts & 1, gcolb = ts * 64;
        const int sl = (tid & 7) ^ ((tid >> 3) & 7);
#pragma unroll
        for (int h2 = 0; h2 < 2; ++h2)            // A halves: 128 rows, 2 gll
#pragma unroll
            for (int j = 0; j < 2; ++j) {
                const int c = j * 512 + tid;
                const int s2 = (c & 7) ^ ((c >> 3) & 7);
                gll16(A + (size_t)(row0 + h2 * 128 + (c >> 3)) * K + gcolb + s2 * 8,
                      lds + d * 32768 + h2 * 16384 + (j * 8 + w) * 1024);
            }
#pragma unroll
        for (int k2 = 0; k2 < 3; ++k2)            // B thirds: 64 rows, 1 gll
            gll16(Bt + (size_t)(col0 + k2 * 64 + (tid >> 3)) * K + gcolb + sl * 8,
                  lds + 65536 + d * 24576 + k2 * 8192 + w * 1024);
    };

#define SB __builtin_amdgcn_sched_barrier(0)
#define WLq(NS) do { asm volatile("s_waitcnt lgkmcnt(" NS ")" ::: "memory"); SB; } while (0)

    stageQ(0);

    for (int t = 0; t < NT; ++t) {
        const char* Ab = lds + (t & 1) * 32768 + abase_l;
        const char* Bb = lds + 65536 + (t & 1) * 24576 + bbase_l;
        asm volatile("s_waitcnt vmcnt(0)" ::: "memory");
        __builtin_amdgcn_s_barrier(); SB;
        // issue 20 reads: a_kk0(4), b_kk0(6), a_kk1(4), b_kk1(6)
#pragma unroll
        for (int i2 = 0; i2 < 4; ++i2) a[i2][0] = *(const s16x8*)(Ab + i2 * 2048 + koff[0]);
#pragma unroll
        for (int n = 0; n < 6; ++n)   b[n][0]  = *(const s16x8*)(Bb + n * 2048 + koff[0]);
        SB;
#pragma unroll
        for (int i2 = 0; i2 < 4; ++i2) a[i2][1] = *(const s16x8*)(Ab + i2 * 2048 + koff[1]);
#pragma unroll
        for (int n = 0; n < 6; ++n)   b[n][1]  = *(const s16x8*)(Bb + n * 2048 + koff[1]);
        SB;
        stageQ(t + 1); SB;
        __builtin_amdgcn_s_setprio(1);
        WLq("10");
#pragma unroll
        for (int i2 = 0; i2 < 4; ++i2)
#pragma unroll
            for (int n = 0; n < 6; ++n)
                acc[i2][n] = __builtin_amdgcn_mfma_f32_16x16x32_bf16(a[i2][0], b[n][0], acc[i2][n], 0, 0, 0);
        SB;
        WLq("0");
#pragma unroll
        for (int i2 = 0; i2 < 4; ++i2)
#pragma unroll
            for (int n = 0; n < 6; ++n)
                acc[i2][n] = __builtin_amdgcn_mfma_f32_16x16x32_bf16(a[i2][1], b[n][1], acc[i2][n], 0, 0, 0);
        __builtin_amdgcn_s_setprio(0); SB;
    }
#undef WLq

    // ---- epilogue: acc -> LDS (bf16, pitch 200), then windowed attention ----
    __builtin_amdgcn_s_barrier();                 // all waves past their WL(0)
    u16* attL = (u16*)lds;
#pragma unroll
    for (int i2 = 0; i2 < 4; ++i2)
#pragma unroll
        for (int n = 0; n < 6; ++n)
#pragma unroll
            for (int j = 0; j < 4; ++j)
                attL[(wr * 64 + i2 * 16 + kg * 4 + j) * 200 + wcg * 96 + n * 16 + lr] =
                    f2b(acc[i2][n][j]);
    __builtin_amdgcn_s_barrier();

    // 8 threads per window: thread j covers cols j*8..j*8+7 of this head
    {
        const int wl = tid >> 3, j = tid & 7;     // 64 windows, 8 threads each
        const float scale = 0.03125f;             // C^-0.5 (d_model quirk)
        u16x8 qv[4], kv[4], vv[4];
#pragma unroll
        for (int t = 0; t < 4; ++t) {
            qv[t] = *(const u16x8*)&attL[(wl * 4 + t) * 200 + j * 8];
            kv[t] = *(const u16x8*)&attL[(wl * 4 + t) * 200 + 64 + j * 8];
            vv[t] = *(const u16x8*)&attL[(wl * 4 + t) * 200 + 128 + j * 8];
        }
        float qf[4][8], kf[4][8];
#pragma unroll
        for (int t = 0; t < 4; ++t)
#pragma unroll
            for (int c = 0; c < 8; ++c) { qf[t][c] = b2f(qv[t][c]); kf[t][c] = b2f(kv[t][c]); }
        float s[4][4];
#pragma unroll
        for (int t = 0; t < 4; ++t)
#pragma unroll
            for (int u2 = 0; u2 < 4; ++u2) {
                float p = qf[t][0] * kf[u2][0];
#pragma unroll
                for (int c = 1; c < 8; ++c) p += qf[t][c] * kf[u2][c];
                p += __shfl_xor(p, 1); p += __shfl_xor(p, 2); p += __shfl_xor(p, 4);
                s[t][u2] = p * scale;
            }
#pragma unroll
        for (int t = 0; t < 4; ++t) {
            const float m = fmaxf(fmaxf(s[t][0], s[t][1]), fmaxf(s[t][2], s[t][3]));
            const float e0 = expf(s[t][0] - m), e1 = expf(s[t][1] - m);
            const float e2 = expf(s[t][2] - m), e3 = expf(s[t][3] - m);
            const float inv = 1.f / (e0 + e1 + e2 + e3);
            u16x8 o;
#pragma unroll
            for (int c = 0; c < 8; ++c)
                o[c] = f2b((e0 * b2f(vv[0][c]) + e1 * b2f(vv[1][c]) +
                            e2 * b2f(vv[2][c]) + e3 * b2f(vv[3][c])) * inv);
            *(u16x8*)(Att + (size_t)(row0 + wl * 4 + t) * 1024 + nb * 64 + j * 8) = o;
        }
    }
#undef SB
}

// ---------- 256x256 8-wave GEMM (r8/r9 schedule) for proj/ff1/ff2 ----------
// MODE 2: gelu(+bias) -> bf16   MODE 3: +bias + bf16 resid -> f32 at natrow
// MODE 5: +bias + bf16 resid -> bf16
template<int MODE>
__global__ __launch_bounds__(512, 2) void gemm256(
    const u16* __restrict__ A, const u16* __restrict__ Bt,
    const float* __restrict__ bias, const void* __restrict__ resid,
    void* __restrict__ Out, int M, int N, int K, int LDA, int NB)
{
    extern __shared__ char lds[];
    const int NT = K >> 6;
    const int nblk = gridDim.x;
    const int x = blockIdx.x & 7, i = blockIdx.x >> 3;
    const int R = (nblk >> 3) / NB;
    const int ncs = NB >> 2;
    const int sc = i >> 4, u = i & 15;
    const int scr = sc / ncs, scc = sc - scr * ncs;
    const int mb = x * R + scr * 4 + (u >> 2);
    const int nb = scc * 4 + (u & 3);
    const int row0 = mb * 256, col0 = nb * 256;
    const int tid = threadIdx.x;
    const int w = tid >> 6, l = tid & 63;
    const int wr = w >> 2, wc = w & 3;
    const int lr = l & 15, kg = l >> 4;
    const int xs = (lr & 7) << 4;
    const int koff[2] = { (kg * 16) ^ xs, (64 + kg * 16) ^ xs };
    const int abase_l = wr * 8192 + lr * 128;
    const int bbase_l = wc * 4096 + lr * 128;

    f32x4 acc[2][2][4][2] = {};
    s16x8 a0[4][2], a1[4][2], b0[2][2], b1[2][2];

    auto stage = [&](int ts, int item) {
        if (ts >= NT) return;
        const int d = ts & 1;
        const int isB = item & 1, h = item >> 1;
        char* lbase = lds + (isB ? 65536 : 0) + d * 32768 + h * 16384;
        const u16* gptr = isB ? Bt : A;
        const int ld = isB ? K : LDA;
        const int blk0 = (isB ? col0 : row0) + h * 128;
#pragma unroll
        for (int j = 0; j < 2; ++j) {
            const int p = j * 512 + tid;
            const int q = p ^ ((p >> 3) & 7);
            gll16(gptr + (size_t)(blk0 + (q >> 3)) * ld + ts * 64 + (q & 7) * 8,
                  lbase + (j * 8 + w) * 1024);
        }
    };

#define SB __builtin_amdgcn_sched_barrier(0)
#define LOAD_A(dst, qm) do { \
    _Pragma("unroll") for (int kk = 0; kk < 2; ++kk) \
    _Pragma("unroll") for (int i2 = 0; i2 < 4; ++i2) \
        dst[i2][kk] = *(const s16x8*)(Ab + (qm) * 16384 + abase_l + i2 * 2048 + koff[kk]); \
} while (0)
#define LOAD_B(dst, qn) do { \
    _Pragma("unroll") for (int kk = 0; kk < 2; ++kk) \
    _Pragma("unroll") for (int n = 0; n < 2; ++n) \
        dst[n][kk] = *(const s16x8*)(Bb + (qn) * 16384 + bbase_l + n * 2048 + koff[kk]); \
} while (0)
#define LGKM0 do { asm volatile("s_waitcnt lgkmcnt(0)" ::: "memory"); SB; } while (0)
#define MFMA_Q(qm, qn, aa, bb) do { \
    __builtin_amdgcn_s_setprio(1); \
    _Pragma("unroll") for (int kk = 0; kk < 2; ++kk) \
    _Pragma("unroll") for (int i2 = 0; i2 < 4; ++i2) \
    _Pragma("unroll") for (int n = 0; n < 2; ++n) \
        acc[qm][qn][i2][n] = __builtin_amdgcn_mfma_f32_16x16x32_bf16( \
            aa[i2][kk], bb[n][kk], acc[qm][qn][i2][n], 0, 0, 0); \
    __builtin_amdgcn_s_setprio(0); SB; \
} while (0)
#define GATE(NSTR) do { \
    asm volatile("s_waitcnt vmcnt(" NSTR ")" ::: "memory"); \
    __builtin_amdgcn_s_barrier(); SB; \
} while (0)

    stage(0, 0); stage(0, 1); stage(0, 2); stage(0, 3);

    for (int t = 0; t < NT - 1; ++t) {
        const char* Ab = lds + (t & 1) * 32768;
        const char* Bb = lds + 65536 + (t & 1) * 32768;
        GATE("4");
        LOAD_A(a0, 0); LOAD_B(b0, 0); SB;
        stage(t + 1, 0); SB;
        LGKM0;
        MFMA_Q(0, 0, a0, b0);
        GATE("4");
        LOAD_A(a1, 1); SB;
        stage(t + 1, 1); SB;
        LGKM0;
        MFMA_Q(1, 0, a1, b0);
        GATE("4");
        LOAD_B(b1, 1); SB;
        stage(t + 1, 2); SB;
        LGKM0;
        MFMA_Q(1, 1, a1, b1);
        stage(t + 1, 3); SB;
        MFMA_Q(0, 1, a0, b1);
    }
    {
        const int t = NT - 1;
        const char* Ab = lds + (t & 1) * 32768;
        const char* Bb = lds + 65536 + (t & 1) * 32768;
        GATE("4");
        LOAD_A(a0, 0); LOAD_B(b0, 0); SB;
        LGKM0;
        MFMA_Q(0, 0, a0, b0);
        GATE("2");
        LOAD_A(a1, 1); SB;
        LGKM0;
        MFMA_Q(1, 0, a1, b0);
        GATE("0");
        LOAD_B(b1, 1); SB;
        LGKM0;
        MFMA_Q(1, 1, a1, b1);
        MFMA_Q(0, 1, a0, b1);
    }
#undef SB
#undef LOAD_A
#undef LOAD_B
#undef LGKM0
#undef MFMA_Q
#undef GATE

#pragma unroll
    for (int qm = 0; qm < 2; ++qm)
#pragma unroll
    for (int i2 = 0; i2 < 4; ++i2) {
        const int grb = row0 + qm * 128 + wr * 64 + i2 * 16 + kg * 4;
#pragma unroll
        for (int qn = 0; qn < 2; ++qn)
#pragma unroll
        for (int n = 0; n < 2; ++n) {
            const int gc = col0 + qn * 128 + wc * 32 + n * 16 + lr;
#pragma unroll
            for (int j = 0; j < 4; ++j) {
                const int gr = grb + j;
                const float v = acc[qm][qn][i2][n][j];
                if (MODE == 2) {
                    const float tt = v + bias[gc];
                    ((u16*)Out)[(size_t)gr * N + gc] = f2b(0.5f * tt * (1.f + erff(tt * 0.70710678118f)));
                } else if (MODE == 3) {
                    ((float*)Out)[(size_t)natrow(gr) * N + gc] =
                        v + bias[gc] + b2f(((const u16*)resid)[(size_t)gr * N + gc]);
                } else {
                    ((u16*)Out)[(size_t)gr * N + gc] =
                        f2b(v + bias[gc] + b2f(((const u16*)resid)[(size_t)gr * N + gc]));
                }
            }
        }
    }
}

// ---------- launch ----------
extern "C" void kernel_launch(void* const* d_in, const int* in_sizes, int n_in,
                              void* d_out, int out_size, void* d_ws, size_t ws_size,
                              hipStream_t stream)
{
    const float* x    = (const float*)d_in[0];
    const float* ln1g = (const float*)d_in[1];
    const float* ln1b = (const float*)d_in[2];
    const float* Wq   = (const float*)d_in[3];
    const float* Wk   = (const float*)d_in[4];
    const float* Wv   = (const float*)d_in[5];
    const float* Wp   = (const float*)d_in[6];
    const float* bp   = (const float*)d_in[7];
    const float* ln2g = (const float*)d_in[8];
    const float* ln2b = (const float*)d_in[9];
    const float* W1   = (const float*)d_in[10];
    const float* b1   = (const float*)d_in[11];
    const float* W2   = (const float*)d_in[12];
    const float* b2   = (const float*)d_in[13];
    float* out = (float*)d_out;

    char* ws = (char*)d_ws;
    const size_t MB = 1024 * 1024;
    u16* xr_b  = (u16*)ws;                        // 32MB: xr bf16 (residual spine)
    u16* xw_b  = (u16*)(ws + 32 * MB);            // 32MB: ln1(x) windowed bf16
    u16* att   = (u16*)(ws + 64 * MB);            // 32MB: fused attn output
    u16* h1b   = (u16*)(ws + 96 * MB);            // 32MB
    u16* ln2bf = (u16*)(ws + 128 * MB);           // 32MB
    u16* WqkvT = (u16*)(ws + 192 * MB);           // 6MB [3072][1024] head-interleaved
    u16* WpT   = (u16*)(ws + 198 * MB);           // 3 x 2MB contiguous
    u16* W1T   = WpT + (1u << 20);
    u16* W2T   = W1T + (1u << 20);

    (void)hipFuncSetAttribute((const void*)gemm_qkv_attn, hipFuncAttributeMaxDynamicSharedMemorySize, 114688);
    (void)hipFuncSetAttribute((const void*)gemm256<2>, hipFuncAttributeMaxDynamicSharedMemorySize, 131072);
    (void)hipFuncSetAttribute((const void*)gemm256<3>, hipFuncAttributeMaxDynamicSharedMemorySize, 131072);
    (void)hipFuncSetAttribute((const void*)gemm256<5>, hipFuncAttributeMaxDynamicSharedMemorySize, 131072);

    const int M = 16384, K = 1024;
    dim3 tpb(32, 8);
    transpose_qkv<<<dim3(2, 32, 48), tpb, 0, stream>>>(Wq, Wk, Wv, WqkvT);
    transpose_pw <<<dim3(32, 32, 3), tpb, 0, stream>>>(Wp, W1, W2, WpT);

    ln_kernel<1, 0><<<16384, 256, 0, stream>>>(x, ln1g, ln1b, xw_b);

    // fused: att = windowed-attention(xw @ [Wq|Wk|Wv])   (1024 blocks = 4 rounds)
    gemm_qkv_attn<<<1024, 512, 114688, stream>>>(xw_b, WqkvT, att, M, K);

    // xr = att @ Wp + bp + xw  -> bf16 spine
    gemm256<5><<<256, 512, 131072, stream>>>(att, WpT, bp, xw_b, xr_b, M, 1024, K, K, 4);

    ln_kernel<0, 1><<<16384, 256, 0, stream>>>(xr_b, ln2g, ln2b, ln2bf);

    // h1 = gelu(ln2 @ W1 + b1)
    gemm256<2><<<256, 512, 131072, stream>>>(ln2bf, W1T, b1, nullptr, h1b, M, 1024, K, K, 4);

    // out[natrow] = h1 @ W2 + b2 + xr
    gemm256<3><<<256, 512, 131072, stream>>>(h1b, W2T, b2, xr_b, out, M, 1024, K, K, 4);
}

// Round 13
// 285.902 us; speedup vs baseline: 1.0919x; 1.0133x over previous
//
#include <hip/hip_runtime.h>
#include <math.h>

typedef unsigned short u16;
typedef unsigned int   u32;

using f32x4  = __attribute__((ext_vector_type(4))) float;
using s16x8  = __attribute__((ext_vector_type(8))) short;
using u16x8  = __attribute__((ext_vector_type(8))) unsigned short;

// ---------- helpers ----------
__device__ __forceinline__ u16 f2b(float f) {           // fp32 -> bf16 RNE
    u32 u = __float_as_uint(f);
    u += 0x7FFFu + ((u >> 16) & 1u);
    return (u16)(u >> 16);
}
__device__ __forceinline__ float b2f(u16 u) { return __uint_as_float(((u32)u) << 16); }

// window-order row R -> natural token row (b*256 + i*16 + j)
__device__ __forceinline__ int natrow(int R) {
    int b = R >> 8, r8 = R & 255, w = r8 >> 2, t = r8 & 3;
    return (b << 8) + ((((w >> 3) << 1) + (t >> 1)) << 4) + ((w & 7) << 1) + (t & 1);
}

__device__ __forceinline__ void gll16(const void* g, void* l) {
    __builtin_amdgcn_global_load_lds(
        (const __attribute__((address_space(1))) void*)g,
        (__attribute__((address_space(3))) void*)l, 16, 0, 0);
}

// ---------- merged prologue: weight transposes + LN1(window-gather) ----------
// bid [0,3072): transpose_qkv  (z=bid>>6: Wq h0-15 | Wk | Wv; head-interleaved out)
// bid [3072,6144): transpose_pw (Wp, W1, W2 -> contiguous)
// bid [6144,22528): ln1 row R = bid-6144, natrow gather, f32 in -> bf16 out
__global__ __launch_bounds__(256) void prologue_kernel(
    const float* __restrict__ x, const float* __restrict__ ln1g, const float* __restrict__ ln1b,
    const float* __restrict__ Wq, const float* __restrict__ Wk, const float* __restrict__ Wv,
    const float* __restrict__ Wp, const float* __restrict__ W1, const float* __restrict__ W2,
    u16* __restrict__ WqkvT, u16* __restrict__ WpT, u16* __restrict__ xw_b)
{
    const int bid = blockIdx.x;
    const int tid = threadIdx.x;
    if (bid < 6144) {
        // ---- transpose role: [R][C] f32 -> [C][R] bf16 ----
        __shared__ float tile[32][33];
        const float* in; u16* out; int Rr, Cc, bx, by;
        if (bid < 3072) {
            const int z = bid >> 6, r = bid & 63;
            bx = r & 1; by = r >> 1;
            in  = (z < 16 ? Wq : z < 32 ? Wk : Wv) + (size_t)(z & 15) * 65536;
            const int h = z & 15, sec = z < 16 ? 0 : (z < 32 ? 1 : 2);
            out = WqkvT + ((size_t)h * 192 + sec * 64) * 1024;
            Rr = 1024; Cc = 64;
        } else {
            const int t = bid - 3072, z = t >> 10, r = t & 1023;
            bx = r & 31; by = r >> 5;
            in  = z == 0 ? Wp : z == 1 ? W1 : W2;
            out = WpT + (size_t)z * 1048576;
            Rr = 1024; Cc = 1024;
        }
        const int tx = tid & 31, ty = tid >> 5;
        const int c  = bx * 32 + tx;
        const int r0 = by * 32;
#pragma unroll
        for (int i = 0; i < 32; i += 8) tile[ty + i][tx] = in[(size_t)(r0 + ty + i) * Cc + c];
        __syncthreads();
        const int orow0 = bx * 32;
        const int ocol  = r0 + tx;
#pragma unroll
        for (int i = 0; i < 32; i += 8)
            out[(size_t)(orow0 + ty + i) * Rr + ocol] = f2b(tile[tx][ty + i]);
    } else {
        // ---- LN1 role ----
        __shared__ float red[8];
        const int R   = bid - 6144;
        const int src = natrow(R);
        const float4 v = ((const float4*)(x + (size_t)src * 1024))[tid];
        float s  = v.x + v.y + v.z + v.w;
        float s2 = v.x * v.x + v.y * v.y + v.z * v.z + v.w * v.w;
#pragma unroll
        for (int o = 32; o; o >>= 1) { s += __shfl_xor(s, o); s2 += __shfl_xor(s2, o); }
        const int w = tid >> 6, l = tid & 63;
        if (l == 0) { red[w] = s; red[w + 4] = s2; }
        __syncthreads();
        s  = red[0] + red[1] + red[2] + red[3];
        s2 = red[4] + red[5] + red[6] + red[7];
        const float mean = s * (1.f / 1024.f);
        const float var  = s2 * (1.f / 1024.f) - mean * mean;
        const float rinv = rsqrtf(var + 1e-5f);
        const float4 gv = ((const float4*)ln1g)[tid];
        const float4 bv = ((const float4*)ln1b)[tid];
        ((ushort4*)(xw_b + (size_t)R * 1024))[tid] = make_ushort4(
            f2b((v.x - mean) * rinv * gv.x + bv.x), f2b((v.y - mean) * rinv * gv.y + bv.y),
            f2b((v.z - mean) * rinv * gv.z + bv.z), f2b((v.w - mean) * rinv * gv.w + bv.w));
    }
}

// ---------- LayerNorm (LN2): bf16 in, bf16 out, identity row map ----------
__global__ __launch_bounds__(256) void ln2_kernel(
    const u16* __restrict__ X, const float* __restrict__ g, const float* __restrict__ bta,
    u16* __restrict__ outB)
{
    const int R = blockIdx.x;
    const ushort4 r = ((const ushort4*)(X + (size_t)R * 1024))[threadIdx.x];
    const float x0 = b2f(r.x), x1 = b2f(r.y), x2 = b2f(r.z), x3 = b2f(r.w);
    float s  = x0 + x1 + x2 + x3;
    float s2 = x0 * x0 + x1 * x1 + x2 * x2 + x3 * x3;
#pragma unroll
    for (int o = 32; o; o >>= 1) { s += __shfl_xor(s, o); s2 += __shfl_xor(s2, o); }
    __shared__ float red[8];
    const int w = threadIdx.x >> 6, l = threadIdx.x & 63;
    if (l == 0) { red[w] = s; red[w + 4] = s2; }
    __syncthreads();
    s  = red[0] + red[1] + red[2] + red[3];
    s2 = red[4] + red[5] + red[6] + red[7];
    const float mean = s * (1.f / 1024.f);
    const float var  = s2 * (1.f / 1024.f) - mean * mean;
    const float rinv = rsqrtf(var + 1e-5f);
    const float4 gv = ((const float4*)g)[threadIdx.x];
    const float4 bv = ((const float4*)bta)[threadIdx.x];
    ((ushort4*)(outB + (size_t)R * 1024))[threadIdx.x] = make_ushort4(
        f2b((x0 - mean) * rinv * gv.x + bv.x), f2b((x1 - mean) * rinv * gv.y + bv.y),
        f2b((x2 - mean) * rinv * gv.z + bv.z), f2b((x3 - mean) * rinv * gv.w + bv.w));
}

// ---------- FUSED QKV GEMM + windowed attention (r12, unchanged) ----------
__global__ __launch_bounds__(512, 2) void gemm_qkv_attn(
    const u16* __restrict__ A, const u16* __restrict__ Bt,
    u16* __restrict__ Att, int M, int K)
{
    extern __shared__ char lds[];
    const int NT = K >> 6;                        // 16
    const int x = blockIdx.x & 7, i = blockIdx.x >> 3;
    const int sc = i >> 4, u = i & 15;
    const int scr = sc >> 2, scc = sc & 3;
    const int mb = x * 8 + scr * 4 + (u >> 2);
    const int nb = scc * 4 + (u & 3);             // head index 0..15
    const int row0 = mb * 256, col0 = nb * 192;
    const int tid = threadIdx.x;
    const int w = tid >> 6, l = tid & 63;
    const int wr = w & 3, wcg = w >> 2;
    const int lr = l & 15, kg = l >> 4;
    const int xs = (lr & 7) << 4;
    const int koff[2] = { (kg * 16) ^ xs, (64 + kg * 16) ^ xs };
    const int abase_l = wr * 8192 + lr * 128;
    const int bbase_l = wcg * 12288 + lr * 128;

    f32x4 acc[4][6] = {};
    s16x8 a[4][2], b[6][2];

    auto stageQ = [&](int ts) {
        if (ts >= NT) return;
        const int d = ts & 1, gcolb = ts * 64;
        const int sl = (tid & 7) ^ ((tid >> 3) & 7);
#pragma unroll
        for (int h2 = 0; h2 < 2; ++h2)
#pragma unroll
            for (int j = 0; j < 2; ++j) {
                const int c = j * 512 + tid;
                const int s2 = (c & 7) ^ ((c >> 3) & 7);
                gll16(A + (size_t)(row0 + h2 * 128 + (c >> 3)) * K + gcolb + s2 * 8,
                      lds + d * 32768 + h2 * 16384 + (j * 8 + w) * 1024);
            }
#pragma unroll
        for (int k2 = 0; k2 < 3; ++k2)
            gll16(Bt + (size_t)(col0 + k2 * 64 + (tid >> 3)) * K + gcolb + sl * 8,
                  lds + 65536 + d * 24576 + k2 * 8192 + w * 1024);
    };

#define SB __builtin_amdgcn_sched_barrier(0)
#define WLq(NS) do { asm volatile("s_waitcnt lgkmcnt(" NS ")" ::: "memory"); SB; } while (0)

    stageQ(0);

    for (int t = 0; t < NT; ++t) {
        const char* Ab = lds + (t & 1) * 32768 + abase_l;
        const char* Bb = lds + 65536 + (t & 1) * 24576 + bbase_l;
        asm volatile("s_waitcnt vmcnt(0)" ::: "memory");
        __builtin_amdgcn_s_barrier(); SB;
#pragma unroll
        for (int i2 = 0; i2 < 4; ++i2) a[i2][0] = *(const s16x8*)(Ab + i2 * 2048 + koff[0]);
#pragma unroll
        for (int n = 0; n < 6; ++n)   b[n][0]  = *(const s16x8*)(Bb + n * 2048 + koff[0]);
        SB;
#pragma unroll
        for (int i2 = 0; i2 < 4; ++i2) a[i2][1] = *(const s16x8*)(Ab + i2 * 2048 + koff[1]);
#pragma unroll
        for (int n = 0; n < 6; ++n)   b[n][1]  = *(const s16x8*)(Bb + n * 2048 + koff[1]);
        SB;
        stageQ(t + 1); SB;
        __builtin_amdgcn_s_setprio(1);
        WLq("10");
#pragma unroll
        for (int i2 = 0; i2 < 4; ++i2)
#pragma unroll
            for (int n = 0; n < 6; ++n)
                acc[i2][n] = __builtin_amdgcn_mfma_f32_16x16x32_bf16(a[i2][0], b[n][0], acc[i2][n], 0, 0, 0);
        SB;
        WLq("0");
#pragma unroll
        for (int i2 = 0; i2 < 4; ++i2)
#pragma unroll
            for (int n = 0; n < 6; ++n)
                acc[i2][n] = __builtin_amdgcn_mfma_f32_16x16x32_bf16(a[i2][1], b[n][1], acc[i2][n], 0, 0, 0);
        __builtin_amdgcn_s_setprio(0); SB;
    }
#undef WLq

    // epilogue: acc -> LDS (bf16, pitch 200) -> windowed attention -> Att
    __builtin_amdgcn_s_barrier();
    u16* attL = (u16*)lds;
#pragma unroll
    for (int i2 = 0; i2 < 4; ++i2)
#pragma unroll
        for (int n = 0; n < 6; ++n)
#pragma unroll
            for (int j = 0; j < 4; ++j)
                attL[(wr * 64 + i2 * 16 + kg * 4 + j) * 200 + wcg * 96 + n * 16 + lr] =
                    f2b(acc[i2][n][j]);
    __builtin_amdgcn_s_barrier();

    {
        const int wl = tid >> 3, j = tid & 7;
        const float scale = 0.03125f;             // C^-0.5 (d_model quirk)
        u16x8 qv[4], kv[4], vv[4];
#pragma unroll
        for (int t = 0; t < 4; ++t) {
            qv[t] = *(const u16x8*)&attL[(wl * 4 + t) * 200 + j * 8];
            kv[t] = *(const u16x8*)&attL[(wl * 4 + t) * 200 + 64 + j * 8];
            vv[t] = *(const u16x8*)&attL[(wl * 4 + t) * 200 + 128 + j * 8];
        }
        float qf[4][8], kf[4][8];
#pragma unroll
        for (int t = 0; t < 4; ++t)
#pragma unroll
            for (int c = 0; c < 8; ++c) { qf[t][c] = b2f(qv[t][c]); kf[t][c] = b2f(kv[t][c]); }
        float s[4][4];
#pragma unroll
        for (int t = 0; t < 4; ++t)
#pragma unroll
            for (int u2 = 0; u2 < 4; ++u2) {
                float p = qf[t][0] * kf[u2][0];
#pragma unroll
                for (int c = 1; c < 8; ++c) p += qf[t][c] * kf[u2][c];
                p += __shfl_xor(p, 1); p += __shfl_xor(p, 2); p += __shfl_xor(p, 4);
                s[t][u2] = p * scale;
            }
#pragma unroll
        for (int t = 0; t < 4; ++t) {
            const float m = fmaxf(fmaxf(s[t][0], s[t][1]), fmaxf(s[t][2], s[t][3]));
            const float e0 = expf(s[t][0] - m), e1 = expf(s[t][1] - m);
            const float e2 = expf(s[t][2] - m), e3 = expf(s[t][3] - m);
            const float inv = 1.f / (e0 + e1 + e2 + e3);
            u16x8 o;
#pragma unroll
            for (int c = 0; c < 8; ++c)
                o[c] = f2b((e0 * b2f(vv[0][c]) + e1 * b2f(vv[1][c]) +
                            e2 * b2f(vv[2][c]) + e3 * b2f(vv[3][c])) * inv);
            *(u16x8*)(Att + (size_t)(row0 + wl * 4 + t) * 1024 + nb * 64 + j * 8) = o;
        }
    }
#undef SB
}

// ---------- 256x256 8-wave GEMM (r8/r9 schedule, unchanged) ----------
// MODE 2: gelu(+bias) -> bf16   MODE 3: +bias + bf16 resid -> f32 at natrow
// MODE 5: +bias + bf16 resid -> bf16
template<int MODE>
__global__ __launch_bounds__(512, 2) void gemm256(
    const u16* __restrict__ A, const u16* __restrict__ Bt,
    const float* __restrict__ bias, const void* __restrict__ resid,
    void* __restrict__ Out, int M, int N, int K, int LDA, int NB)
{
    extern __shared__ char lds[];
    const int NT = K >> 6;
    const int nblk = gridDim.x;
    const int x = blockIdx.x & 7, i = blockIdx.x >> 3;
    const int R = (nblk >> 3) / NB;
    const int ncs = NB >> 2;
    const int sc = i >> 4, u = i & 15;
    const int scr = sc / ncs, scc = sc - scr * ncs;
    const int mb = x * R + scr * 4 + (u >> 2);
    const int nb = scc * 4 + (u & 3);
    const int row0 = mb * 256, col0 = nb * 256;
    const int tid = threadIdx.x;
    const int w = tid >> 6, l = tid & 63;
    const int wr = w >> 2, wc = w & 3;
    const int lr = l & 15, kg = l >> 4;
    const int xs = (lr & 7) << 4;
    const int koff[2] = { (kg * 16) ^ xs, (64 + kg * 16) ^ xs };
    const int abase_l = wr * 8192 + lr * 128;
    const int bbase_l = wc * 4096 + lr * 128;

    f32x4 acc[2][2][4][2] = {};
    s16x8 a0[4][2], a1[4][2], b0[2][2], b1[2][2];

    auto stage = [&](int ts, int item) {
        if (ts >= NT) return;
        const int d = ts & 1;
        const int isB = item & 1, h = item >> 1;
        char* lbase = lds + (isB ? 65536 : 0) + d * 32768 + h * 16384;
        const u16* gptr = isB ? Bt : A;
        const int ld = isB ? K : LDA;
        const int blk0 = (isB ? col0 : row0) + h * 128;
#pragma unroll
        for (int j = 0; j < 2; ++j) {
            const int p = j * 512 + tid;
            const int q = p ^ ((p >> 3) & 7);
            gll16(gptr + (size_t)(blk0 + (q >> 3)) * ld + ts * 64 + (q & 7) * 8,
                  lbase + (j * 8 + w) * 1024);
        }
    };

#define SB __builtin_amdgcn_sched_barrier(0)
#define LOAD_A(dst, qm) do { \
    _Pragma("unroll") for (int kk = 0; kk < 2; ++kk) \
    _Pragma("unroll") for (int i2 = 0; i2 < 4; ++i2) \
        dst[i2][kk] = *(const s16x8*)(Ab + (qm) * 16384 + abase_l + i2 * 2048 + koff[kk]); \
} while (0)
#define LOAD_B(dst, qn) do { \
    _Pragma("unroll") for (int kk = 0; kk < 2; ++kk) \
    _Pragma("unroll") for (int n = 0; n < 2; ++n) \
        dst[n][kk] = *(const s16x8*)(Bb + (qn) * 16384 + bbase_l + n * 2048 + koff[kk]); \
} while (0)
#define LGKM0 do { asm volatile("s_waitcnt lgkmcnt(0)" ::: "memory"); SB; } while (0)
#define MFMA_Q(qm, qn, aa, bb) do { \
    __builtin_amdgcn_s_setprio(1); \
    _Pragma("unroll") for (int kk = 0; kk < 2; ++kk) \
    _Pragma("unroll") for (int i2 = 0; i2 < 4; ++i2) \
    _Pragma("unroll") for (int n = 0; n < 2; ++n) \
        acc[qm][qn][i2][n] = __builtin_amdgcn_mfma_f32_16x16x32_bf16( \
            aa[i2][kk], bb[n][kk], acc[qm][qn][i2][n], 0, 0, 0); \
    __builtin_amdgcn_s_setprio(0); SB; \
} while (0)
#define GATE(NSTR) do { \
    asm volatile("s_waitcnt vmcnt(" NSTR ")" ::: "memory"); \
    __builtin_amdgcn_s_barrier(); SB; \
} while (0)

    stage(0, 0); stage(0, 1); stage(0, 2); stage(0, 3);

    for (int t = 0; t < NT - 1; ++t) {
        const char* Ab = lds + (t & 1) * 32768;
        const char* Bb = lds + 65536 + (t & 1) * 32768;
        GATE("4");
        LOAD_A(a0, 0); LOAD_B(b0, 0); SB;
        stage(t + 1, 0); SB;
        LGKM0;
        MFMA_Q(0, 0, a0, b0);
        GATE("4");
        LOAD_A(a1, 1); SB;
        stage(t + 1, 1); SB;
        LGKM0;
        MFMA_Q(1, 0, a1, b0);
        GATE("4");
        LOAD_B(b1, 1); SB;
        stage(t + 1, 2); SB;
        LGKM0;
        MFMA_Q(1, 1, a1, b1);
        stage(t + 1, 3); SB;
        MFMA_Q(0, 1, a0, b1);
    }
    {
        const int t = NT - 1;
        const char* Ab = lds + (t & 1) * 32768;
        const char* Bb = lds + 65536 + (t & 1) * 32768;
        GATE("4");
        LOAD_A(a0, 0); LOAD_B(b0, 0); SB;
        LGKM0;
        MFMA_Q(0, 0, a0, b0);
        GATE("2");
        LOAD_A(a1, 1); SB;
        LGKM0;
        MFMA_Q(1, 0, a1, b0);
        GATE("0");
        LOAD_B(b1, 1); SB;
        LGKM0;
        MFMA_Q(1, 1, a1, b1);
        MFMA_Q(0, 1, a0, b1);
    }
#undef SB
#undef LOAD_A
#undef LOAD_B
#undef LGKM0
#undef MFMA_Q
#undef GATE

#pragma unroll
    for (int qm = 0; qm < 2; ++qm)
#pragma unroll
    for (int i2 = 0; i2 < 4; ++i2) {
        const int grb = row0 + qm * 128 + wr * 64 + i2 * 16 + kg * 4;
#pragma unroll
        for (int qn = 0; qn < 2; ++qn)
#pragma unroll
        for (int n = 0; n < 2; ++n) {
            const int gc = col0 + qn * 128 + wc * 32 + n * 16 + lr;
#pragma unroll
            for (int j = 0; j < 4; ++j) {
                const int gr = grb + j;
                const float v = acc[qm][qn][i2][n][j];
                if (MODE == 2) {
                    const float tt = v + bias[gc];
                    ((u16*)Out)[(size_t)gr * N + gc] = f2b(0.5f * tt * (1.f + erff(tt * 0.70710678118f)));
                } else if (MODE == 3) {
                    ((float*)Out)[(size_t)natrow(gr) * N + gc] =
                        v + bias[gc] + b2f(((const u16*)resid)[(size_t)gr * N + gc]);
                } else {
                    ((u16*)Out)[(size_t)gr * N + gc] =
                        f2b(v + bias[gc] + b2f(((const u16*)resid)[(size_t)gr * N + gc]));
                }
            }
        }
    }
}

// ---------- launch ----------
extern "C" void kernel_launch(void* const* d_in, const int* in_sizes, int n_in,
                              void* d_out, int out_size, void* d_ws, size_t ws_size,
                              hipStream_t stream)
{
    const float* x    = (const float*)d_in[0];
    const float* ln1g = (const float*)d_in[1];
    const float* ln1b = (const float*)d_in[2];
    const float* Wq   = (const float*)d_in[3];
    const float* Wk   = (const float*)d_in[4];
    const float* Wv   = (const float*)d_in[5];
    const float* Wp   = (const float*)d_in[6];
    const float* bp   = (const float*)d_in[7];
    const float* ln2g = (const float*)d_in[8];
    const float* ln2b = (const float*)d_in[9];
    const float* W1   = (const float*)d_in[10];
    const float* b1   = (const float*)d_in[11];
    const float* W2   = (const float*)d_in[12];
    const float* b2   = (const float*)d_in[13];
    float* out = (float*)d_out;

    char* ws = (char*)d_ws;
    const size_t MB = 1024 * 1024;
    u16* xr_b  = (u16*)ws;                        // 32MB: xr bf16 (residual spine)
    u16* xw_b  = (u16*)(ws + 32 * MB);            // 32MB: ln1(x) windowed bf16
    u16* att   = (u16*)(ws + 64 * MB);            // 32MB: fused attn output
    u16* h1b   = (u16*)(ws + 96 * MB);            // 32MB
    u16* ln2bf = (u16*)(ws + 128 * MB);           // 32MB
    u16* WqkvT = (u16*)(ws + 192 * MB);           // 6MB [3072][1024] head-interleaved
    u16* WpT   = (u16*)(ws + 198 * MB);           // 3 x 2MB contiguous
    u16* W1T   = WpT + (1u << 20);
    u16* W2T   = W1T + (1u << 20);

    (void)hipFuncSetAttribute((const void*)gemm_qkv_attn, hipFuncAttributeMaxDynamicSharedMemorySize, 114688);
    (void)hipFuncSetAttribute((const void*)gemm256<2>, hipFuncAttributeMaxDynamicSharedMemorySize, 131072);
    (void)hipFuncSetAttribute((const void*)gemm256<3>, hipFuncAttributeMaxDynamicSharedMemorySize, 131072);
    (void)hipFuncSetAttribute((const void*)gemm256<5>, hipFuncAttributeMaxDynamicSharedMemorySize, 131072);

    const int M = 16384, K = 1024;

    // merged prologue: weight transposes + LN1 (one launch, 22528 blocks)
    prologue_kernel<<<22528, 256, 0, stream>>>(x, ln1g, ln1b, Wq, Wk, Wv,
                                               Wp, W1, W2, WqkvT, WpT, xw_b);

    // fused: att = windowed-attention(xw @ [Wq|Wk|Wv])
    gemm_qkv_attn<<<1024, 512, 114688, stream>>>(xw_b, WqkvT, att, M, K);

    // xr = att @ Wp + bp + xw  -> bf16 spine
    gemm256<5><<<256, 512, 131072, stream>>>(att, WpT, bp, xw_b, xr_b, M, 1024, K, K, 4);

    ln2_kernel<<<16384, 256, 0, stream>>>(xr_b, ln2g, ln2b, ln2bf);

    // h1 = gelu(ln2 @ W1 + b1)
    gemm256<2><<<256, 512, 131072, stream>>>(ln2bf, W1T, b1, nullptr, h1b, M, 1024, K, K, 4);

    // out[natrow] = h1 @ W2 + b2 + xr
    gemm256<3><<<256, 512, 131072, stream>>>(h1b, W2T, b2, xr_b, out, M, 1024, K, K, 4);
}